// Round 4
// baseline (3075.926 us; speedup 1.0000x reference)
//
#include <hip/hip_runtime.h>
#include <math.h>

#define NPTS 16384
#define NCTR 1024
#define BATCH 8

// Bit-exact squared distance matching numpy: ((dx*dx + dy*dy) + dz*dz),
// each op individually IEEE-rounded (no FMA contraction).
__device__ __forceinline__ float sq_dist(float x, float y, float z,
                                         float cx, float cy, float cz) {
  float dx = __fsub_rn(x, cx);
  float dy = __fsub_rn(y, cy);
  float dz = __fsub_rn(z, cz);
  return __fadd_rn(__fadd_rn(__fmul_rn(dx, dx), __fmul_rn(dy, dy)), __fmul_rn(dz, dz));
}

__device__ __forceinline__ float silu_f(float x) {
  return x / (1.0f + __expf(-x));
}

// X-macro over the 32 per-thread points. R1-R3 post-mortem: float px[32]
// NEVER became registers — SROA runs before loop unrolling, sees runtime
// indices, leaves the allocas in scratch (VGPR_Count 64/84/88 with 800MB
// of HBM spill-reload traffic, invariant under launch-bounds changes).
// Named scalars are plain SSA values; mem2reg promotes them unconditionally.
#define PT_LIST(F) \
  F(0)  F(1)  F(2)  F(3)  F(4)  F(5)  F(6)  F(7)  \
  F(8)  F(9)  F(10) F(11) F(12) F(13) F(14) F(15) \
  F(16) F(17) F(18) F(19) F(20) F(21) F(22) F(23) \
  F(24) F(25) F(26) F(27) F(28) F(29) F(30) F(31)

// ---------------------------------------------------------------------------
// Kernel 1: farthest point sampling. One block per batch, 512 threads,
// 32 points/thread in named scalar registers (~170 VGPRs). waves_per_eu(2,2)
// gives the RA a 256-VGPR budget so it has no reason to re-spill.
// One barrier per step: wave argmax -> LDS (parity double-buffered) ->
// barrier -> redundant 8-way reduce in every thread -> centroid re-fetched
// from global via readfirstlane (uniform scalar load, L2-warm).
// Tie-break matches jnp.argmax first-occurrence: value desc, index asc.
// ---------------------------------------------------------------------------
__global__ __launch_bounds__(512)
__attribute__((amdgpu_waves_per_eu(2, 2)))
void fps_kernel(const float* __restrict__ xyz, int* __restrict__ fps_idx) {
  const int b = blockIdx.x;
  const int t = threadIdx.x;
  const float* X = xyz + (size_t)b * 3 * NPTS;
  const float* Y = X + NPTS;
  const float* Z = X + 2 * NPTS;

#define DECL_PT(j) float px##j, py##j, pz##j, dist##j;
  PT_LIST(DECL_PT)
#undef DECL_PT

#define INIT_PT(j)                 \
  {                                \
    const int n = t + (j << 9);    \
    px##j = X[n];                  \
    py##j = Y[n];                  \
    pz##j = Z[n];                  \
    dist##j = __builtin_inff();    \
  }
  PT_LIST(INIT_PT)
#undef INIT_PT

  __shared__ float s_v[16];  // [parity][8 waves]
  __shared__ int s_n[16];
  const int w = t >> 6;
  const int lane = t & 63;

  if (t == 0) fps_idx[b * NCTR] = 0;
  // first centroid = point 0 (uniform broadcast load)
  float cx = X[0], cy = Y[0], cz = Z[0];

  for (int i = 1; i < NCTR; ++i) {
    float bv = -__builtin_inff();
    int bj = 0;
    // scan j ascending; strict > keeps the smallest j on ties
#define STEP_PT(j)                                            \
  {                                                           \
    const float d = sq_dist(px##j, py##j, pz##j, cx, cy, cz); \
    dist##j = fminf(dist##j, d);                              \
    const bool c = dist##j > bv;                              \
    bv = c ? dist##j : bv;                                    \
    bj = c ? j : bj;                                          \
  }
    PT_LIST(STEP_PT)
#undef STEP_PT
    int bn = (bj << 9) + t;  // global point index; n-order == (j,t) scan order

    // wave-level argmax, 64 lanes: value desc, index asc
#pragma unroll
    for (int off = 32; off >= 1; off >>= 1) {
      const float ov = __shfl_down(bv, off);
      const int on = __shfl_down(bn, off);
      if (ov > bv || (ov == bv && on < bn)) { bv = ov; bn = on; }
    }
    const int base = (i & 1) << 3;
    if (lane == 0) { s_v[base + w] = bv; s_n[base + w] = bn; }
    __syncthreads();  // the ONLY barrier per step

    // every thread redundantly reduces the 8 wave candidates (broadcast reads)
    float v0 = s_v[base + 0];
    int n0 = s_n[base + 0];
#pragma unroll
    for (int q = 1; q < 8; ++q) {
      const float vq = s_v[base + q];
      const int nq = s_n[base + q];
      if (vq > v0 || (vq == v0 && nq < n0)) { v0 = vq; n0 = nq; }
    }
    if (t == 0) fps_idx[b * NCTR + i] = n0;

    // all threads fetch winner coords from global (uniform -> scalar load);
    // avoids dynamic register indexing AND a second barrier.
    const int nu = __builtin_amdgcn_readfirstlane(n0);
    cx = X[nu];
    cy = Y[nu];
    cz = Z[nu];
  }
}

// ---------------------------------------------------------------------------
// Kernel 2: ball query. One wave per centroid; scan points in ascending index
// order, collect first 32 with dist <= r^2, pad with first hit.
// ---------------------------------------------------------------------------
__global__ __launch_bounds__(256) void ballq_kernel(const float* __restrict__ xyz,
                                                    const int* __restrict__ fps_idx,
                                                    int* __restrict__ ball_idx) {
  const int gw = (blockIdx.x * 256 + threadIdx.x) >> 6;  // 0..8191
  const int lane = threadIdx.x & 63;
  const int b = gw >> 10;
  const float* X = xyz + (size_t)b * 3 * NPTS;
  const float* Y = X + NPTS;
  const float* Z = X + 2 * NPTS;
  const int c = fps_idx[gw];
  const float cx = X[c], cy = Y[c], cz = Z[c];
  int* out = ball_idx + (size_t)gw * 32;
  const float R2 = 0.04f;

  int cnt = 0, first = -1;
  for (int base = 0; base < NPTS; base += 64) {
    const int j = base + lane;
    const float d = sq_dist(X[j], Y[j], Z[j], cx, cy, cz);
    const bool inb = !(d > R2);
    const unsigned long long m = __ballot(inb);
    if (first < 0 && m != 0ull) first = base + __ffsll(m) - 1;
    if (inb) {
      const int pos = cnt + __popcll(m & ((1ull << lane) - 1ull));
      if (pos < 32) out[pos] = j;
    }
    cnt += __popcll(m);
    if (cnt >= 32) break;
  }
  for (int k = cnt + lane; k < 32; k += 64) out[k] = first;
}

// ---------------------------------------------------------------------------
// Kernel 3: fused gather + 3-layer pointwise MLP + mean over 32 samples.
// One block per (b, s) group, 256 threads. Activations LDS channel-major
// [c][36] (float4 over k); weights staged transposed [c][o] per layer.
// ---------------------------------------------------------------------------
__global__ __launch_bounds__(256, 2) void mlp_kernel(
    const float* __restrict__ xyz, const float* __restrict__ points,
    const int* __restrict__ fps_idx, const int* __restrict__ ball_idx,
    const float* __restrict__ w0, const float* __restrict__ b0,
    const float* __restrict__ w1, const float* __restrict__ b1,
    const float* __restrict__ w2, const float* __restrict__ b2,
    float* __restrict__ out) {
  const int s = blockIdx.x, b = blockIdx.y, t = threadIdx.x;

  __shared__ float A1[64 * 36];    // layer0 out [o][k]
  __shared__ float A2[128 * 36];   // layer1 out [o][k]
  __shared__ float S[8704];        // scratch: A0+Wt0 | Wt1 | Wt2 chunk
  __shared__ float bias_sh[256];
  __shared__ int jidx[32];
  __shared__ float ctr[3];

  const int g = b * NCTR + s;

  // phase 1: indices, centroid, Wt0 ([c][68] o-transposed), bias0
  if (t < 32) jidx[t] = ball_idx[(size_t)g * 32 + t];
  if (t < 3) ctr[t] = xyz[((size_t)b * 3 + t) * NPTS + fps_idx[g]];
  float* A0 = S;              // [67][36]
  float* Wt0 = S + 67 * 36;   // [67][68]
  for (int e = t; e < 67 * 64; e += 256) {
    int o = e / 67, c = e - o * 67;
    Wt0[c * 68 + o] = w0[e];
  }
  if (t < 64) bias_sh[t] = b0[t];
  __syncthreads();

  // phase 2: gather A0 = [xyz_norm(3); points(64)] x 32 samples
  for (int e = t; e < 67 * 32; e += 256) {
    int c = e >> 5, k = e & 31;
    int j = jidx[k];
    float v;
    if (c < 3)
      v = xyz[((size_t)b * 3 + c) * NPTS + j] - ctr[c];
    else
      v = points[((size_t)b * 64 + (c - 3)) * NPTS + j];
    A0[c * 36 + k] = v;
  }
  __syncthreads();

  // phase 3: layer 0 (67 -> 64), tile 4k x 2o
  {
    const int o0 = (t & 31) * 2;
    const int k0 = (t >> 5) * 4;
    float acc[4][2] = {{0.f, 0.f}, {0.f, 0.f}, {0.f, 0.f}, {0.f, 0.f}};
    for (int c = 0; c < 67; ++c) {
      const float4 a = *(const float4*)(A0 + c * 36 + k0);
      const float wv0 = Wt0[c * 68 + o0];
      const float wv1 = Wt0[c * 68 + o0 + 1];
      acc[0][0] = fmaf(a.x, wv0, acc[0][0]);
      acc[1][0] = fmaf(a.y, wv0, acc[1][0]);
      acc[2][0] = fmaf(a.z, wv0, acc[2][0]);
      acc[3][0] = fmaf(a.w, wv0, acc[3][0]);
      acc[0][1] = fmaf(a.x, wv1, acc[0][1]);
      acc[1][1] = fmaf(a.y, wv1, acc[1][1]);
      acc[2][1] = fmaf(a.z, wv1, acc[2][1]);
      acc[3][1] = fmaf(a.w, wv1, acc[3][1]);
    }
#pragma unroll
    for (int i = 0; i < 2; ++i) {
      const float bb = bias_sh[o0 + i];
      float4 r;
      r.x = silu_f(acc[0][i] + bb);
      r.y = silu_f(acc[1][i] + bb);
      r.z = silu_f(acc[2][i] + bb);
      r.w = silu_f(acc[3][i] + bb);
      *(float4*)(A1 + (o0 + i) * 36 + k0) = r;
    }
  }
  __syncthreads();

  // phase 4: stage Wt1 [64][132], bias1
  float* Wt1 = S;
  for (int e = t; e < 128 * 64; e += 256) {
    int o = e >> 6, c = e & 63;
    Wt1[c * 132 + o] = w1[e];
  }
  if (t < 128) bias_sh[t] = b1[t];
  __syncthreads();

  // phase 5: layer 1 (64 -> 128), tile 4k x 4o
  {
    const int o0 = (t & 31) * 4;
    const int k0 = (t >> 5) * 4;
    float acc[4][4];
#pragma unroll
    for (int kk = 0; kk < 4; ++kk)
#pragma unroll
      for (int oo = 0; oo < 4; ++oo) acc[kk][oo] = 0.f;
    for (int c = 0; c < 64; ++c) {
      const float4 a = *(const float4*)(A1 + c * 36 + k0);
      const float4 w = *(const float4*)(Wt1 + c * 132 + o0);
      const float av[4] = {a.x, a.y, a.z, a.w};
      const float wv[4] = {w.x, w.y, w.z, w.w};
#pragma unroll
      for (int kk = 0; kk < 4; ++kk)
#pragma unroll
        for (int oo = 0; oo < 4; ++oo)
          acc[kk][oo] = fmaf(av[kk], wv[oo], acc[kk][oo]);
    }
#pragma unroll
    for (int oo = 0; oo < 4; ++oo) {
      const float bb = bias_sh[o0 + oo];
      float4 r;
      r.x = silu_f(acc[0][oo] + bb);
      r.y = silu_f(acc[1][oo] + bb);
      r.z = silu_f(acc[2][oo] + bb);
      r.w = silu_f(acc[3][oo] + bb);
      *(float4*)(A2 + (o0 + oo) * 36 + k0) = r;
    }
  }
  __syncthreads();

  // phase 6: layer 2 (128 -> 256) in 4 chunks of 64 outputs + mean over k
  float* Wt2 = S;   // [128][68] per chunk
  float* P = A1;    // partial sums [64][9] (A1 dead)
  const int o0 = (t & 31) * 2;
  const int k0 = (t >> 5) * 4;
  const int kg = t >> 5;
  for (int chunk = 0; chunk < 4; ++chunk) {
    for (int e = t; e < 64 * 128; e += 256) {
      int o = e >> 7, c = e & 127;
      Wt2[c * 68 + o] = w2[chunk * 8192 + e];
    }
    if (t < 64) bias_sh[t] = b2[chunk * 64 + t];
    __syncthreads();

    float acc[4][2] = {{0.f, 0.f}, {0.f, 0.f}, {0.f, 0.f}, {0.f, 0.f}};
    for (int c = 0; c < 128; ++c) {
      const float4 a = *(const float4*)(A2 + c * 36 + k0);
      const float wv0 = Wt2[c * 68 + o0];
      const float wv1 = Wt2[c * 68 + o0 + 1];
      acc[0][0] = fmaf(a.x, wv0, acc[0][0]);
      acc[1][0] = fmaf(a.y, wv0, acc[1][0]);
      acc[2][0] = fmaf(a.z, wv0, acc[2][0]);
      acc[3][0] = fmaf(a.w, wv0, acc[3][0]);
      acc[0][1] = fmaf(a.x, wv1, acc[0][1]);
      acc[1][1] = fmaf(a.y, wv1, acc[1][1]);
      acc[2][1] = fmaf(a.z, wv1, acc[2][1]);
      acc[3][1] = fmaf(a.w, wv1, acc[3][1]);
    }
#pragma unroll
    for (int i = 0; i < 2; ++i) {
      const float bb = bias_sh[o0 + i];
      float sum = silu_f(acc[0][i] + bb) + silu_f(acc[1][i] + bb) +
                  silu_f(acc[2][i] + bb) + silu_f(acc[3][i] + bb);
      P[(o0 + i) * 9 + kg] = sum;
    }
    __syncthreads();
    if (t < 64) {
      float tot = 0.f;
#pragma unroll
      for (int q = 0; q < 8; ++q) tot += P[t * 9 + q];
      out[((size_t)b * 256 + chunk * 64 + t) * NCTR + s] = tot * (1.0f / 32.0f);
    }
    __syncthreads();
  }
}

extern "C" void kernel_launch(void* const* d_in, const int* in_sizes, int n_in,
                              void* d_out, int out_size, void* d_ws, size_t ws_size,
                              hipStream_t stream) {
  const float* xyz = (const float*)d_in[0];
  const float* points = (const float*)d_in[1];
  const float* w0 = (const float*)d_in[2];
  const float* b0 = (const float*)d_in[3];
  const float* w1 = (const float*)d_in[4];
  const float* b1 = (const float*)d_in[5];
  const float* w2 = (const float*)d_in[6];
  const float* b2 = (const float*)d_in[7];
  float* out = (float*)d_out;

  int* fps = (int*)d_ws;           // 8*1024 ints
  int* bidx = (int*)d_ws + 8192;   // 8*1024*32 ints

  fps_kernel<<<BATCH, 512, 0, stream>>>(xyz, fps);
  ballq_kernel<<<2048, 256, 0, stream>>>(xyz, fps, bidx);
  mlp_kernel<<<dim3(NCTR, BATCH), 256, 0, stream>>>(xyz, points, fps, bidx,
                                                    w0, b0, w1, b1, w2, b2, out);
}

// Round 5
// 3063.863 us; speedup vs baseline: 1.0039x; 1.0039x over previous
//
#include <hip/hip_runtime.h>
#include <math.h>

#define NPTS 16384
#define NCTR 1024
#define BATCH 8

// Bit-exact squared distance matching numpy: ((dx*dx + dy*dy) + dz*dz),
// each op individually IEEE-rounded (no FMA contraction).
__device__ __forceinline__ float sq_dist(float x, float y, float z,
                                         float cx, float cy, float cz) {
  float dx = __fsub_rn(x, cx);
  float dy = __fsub_rn(y, cy);
  float dz = __fsub_rn(z, cz);
  return __fadd_rn(__fadd_rn(__fmul_rn(dx, dx), __fmul_rn(dy, dy)), __fmul_rn(dz, dz));
}

__device__ __forceinline__ float silu_f(float x) {
  return x / (1.0f + __expf(-x));
}

#define PT_LIST(F) \
  F(0)  F(1)  F(2)  F(3)  F(4)  F(5)  F(6)  F(7)  \
  F(8)  F(9)  F(10) F(11) F(12) F(13) F(14) F(15) \
  F(16) F(17) F(18) F(19) F(20) F(21) F(22) F(23) \
  F(24) F(25) F(26) F(27) F(28) F(29) F(30) F(31)

// ---------------------------------------------------------------------------
// Kernel 1: farthest point sampling. One block per batch, 512 threads,
// 32 points/thread.
// R4 post-mortem: WRITE_SIZE==32KB (output only) proved the compiler was
// REMATERIALIZING the xyz loads inside the step loop (1.6GB of re-reads,
// 822MB HBM), not spilling. Fix: pin the loaded coords through an empty
// asm volatile — asm-defined values cannot be remat'd, forcing true VGPR
// residency (~190 regs, fits the waves_per_eu(2,2) budget of 256).
// Tie-break matches jnp.argmax first-occurrence: value desc, index asc.
// ---------------------------------------------------------------------------
__global__ __launch_bounds__(512)
__attribute__((amdgpu_waves_per_eu(2, 2)))
void fps_kernel(const float* __restrict__ xyz, int* __restrict__ fps_idx) {
  const int b = blockIdx.x;
  const int t = threadIdx.x;
  const float* X = xyz + (size_t)b * 3 * NPTS;
  const float* Y = X + NPTS;
  const float* Z = X + 2 * NPTS;

#define DECL_PT(j) float px##j, py##j, pz##j, dist##j;
  PT_LIST(DECL_PT)
#undef DECL_PT

#define INIT_PT(j)                 \
  {                                \
    const int n = t + (j << 9);    \
    px##j = X[n];                  \
    py##j = Y[n];                  \
    pz##j = Z[n];                  \
    dist##j = __builtin_inff();    \
  }
  PT_LIST(INIT_PT)
#undef INIT_PT

  // Opaque pin: the compiler can no longer re-derive these from memory,
  // so they must stay live in registers across the whole step loop.
#define PIN_PT(j) asm volatile("" : "+v"(px##j), "+v"(py##j), "+v"(pz##j));
  PT_LIST(PIN_PT)
#undef PIN_PT

  __shared__ float s_v[16];  // [parity][8 waves]
  __shared__ int s_n[16];
  const int w = t >> 6;
  const int lane = t & 63;

  if (t == 0) fps_idx[b * NCTR] = 0;
  // first centroid = point 0 (uniform broadcast load)
  float cx = X[0], cy = Y[0], cz = Z[0];

  for (int i = 1; i < NCTR; ++i) {
    float bv = -__builtin_inff();
    int bj = 0;
    // scan j ascending; strict > keeps the smallest j on ties
#define STEP_PT(j)                                            \
  {                                                           \
    const float d = sq_dist(px##j, py##j, pz##j, cx, cy, cz); \
    dist##j = fminf(dist##j, d);                              \
    const bool c = dist##j > bv;                              \
    bv = c ? dist##j : bv;                                    \
    bj = c ? j : bj;                                          \
  }
    PT_LIST(STEP_PT)
#undef STEP_PT
    int bn = (bj << 9) + t;  // global point index; n-order == (j,t) scan order

    // wave-level argmax, 64 lanes: value desc, index asc
#pragma unroll
    for (int off = 32; off >= 1; off >>= 1) {
      const float ov = __shfl_down(bv, off);
      const int on = __shfl_down(bn, off);
      if (ov > bv || (ov == bv && on < bn)) { bv = ov; bn = on; }
    }
    const int base = (i & 1) << 3;
    if (lane == 0) { s_v[base + w] = bv; s_n[base + w] = bn; }
    __syncthreads();  // the ONLY barrier per step

    // every thread redundantly reduces the 8 wave candidates (broadcast reads)
    float v0 = s_v[base + 0];
    int n0 = s_n[base + 0];
#pragma unroll
    for (int q = 1; q < 8; ++q) {
      const float vq = s_v[base + q];
      const int nq = s_n[base + q];
      if (vq > v0 || (vq == v0 && nq < n0)) { v0 = vq; n0 = nq; }
    }
    if (t == 0) fps_idx[b * NCTR + i] = n0;

    // all threads fetch winner coords from global (uniform -> scalar load)
    const int nu = __builtin_amdgcn_readfirstlane(n0);
    cx = X[nu];
    cy = Y[nu];
    cz = Z[nu];
  }
}

// ---------------------------------------------------------------------------
// Kernel 2: ball query. One wave per centroid; scan points in ascending index
// order, collect first 32 with dist <= r^2, pad with first hit.
// ---------------------------------------------------------------------------
__global__ __launch_bounds__(256) void ballq_kernel(const float* __restrict__ xyz,
                                                    const int* __restrict__ fps_idx,
                                                    int* __restrict__ ball_idx) {
  const int gw = (blockIdx.x * 256 + threadIdx.x) >> 6;  // 0..8191
  const int lane = threadIdx.x & 63;
  const int b = gw >> 10;
  const float* X = xyz + (size_t)b * 3 * NPTS;
  const float* Y = X + NPTS;
  const float* Z = X + 2 * NPTS;
  const int c = fps_idx[gw];
  const float cx = X[c], cy = Y[c], cz = Z[c];
  int* out = ball_idx + (size_t)gw * 32;
  const float R2 = 0.04f;

  int cnt = 0, first = -1;
  for (int base = 0; base < NPTS; base += 64) {
    const int j = base + lane;
    const float d = sq_dist(X[j], Y[j], Z[j], cx, cy, cz);
    const bool inb = !(d > R2);
    const unsigned long long m = __ballot(inb);
    if (first < 0 && m != 0ull) first = base + __ffsll(m) - 1;
    if (inb) {
      const int pos = cnt + __popcll(m & ((1ull << lane) - 1ull));
      if (pos < 32) out[pos] = j;
    }
    cnt += __popcll(m);
    if (cnt >= 32) break;
  }
  for (int k = cnt + lane; k < 32; k += 64) out[k] = first;
}

// ---------------------------------------------------------------------------
// Kernel 2b: one-off weight transpose into workspace: wt[c][o] layouts.
// Lets mlp stage weights with coalesced global reads AND stride-1 LDS
// writes (R3/R4 showed 3.9e7 LDS bank-conflict cycles from the strided
// in-kernel transpose writes).
// ---------------------------------------------------------------------------
__global__ __launch_bounds__(256) void transpose_w_kernel(
    const float* __restrict__ w0, const float* __restrict__ w1,
    const float* __restrict__ w2, float* __restrict__ wt0,
    float* __restrict__ wt1, float* __restrict__ wt2) {
  const int t0 = blockIdx.x * 256 + threadIdx.x;
  const int stride = gridDim.x * 256;
  for (int e = t0; e < 64 * 67; e += stride) {
    int o = e / 67, c = e - o * 67;
    wt0[c * 64 + o] = w0[e];
  }
  for (int e = t0; e < 128 * 64; e += stride) {
    int o = e >> 6, c = e & 63;
    wt1[c * 128 + o] = w1[e];
  }
  for (int e = t0; e < 256 * 128; e += stride) {
    int o = e >> 7, c = e & 127;
    wt2[c * 256 + o] = w2[e];
  }
}

// ---------------------------------------------------------------------------
// Kernel 3: fused gather + 3-layer pointwise MLP + mean over 32 samples.
// One block per (b, s) group, 256 threads. Activations LDS channel-major
// [c][36] (float4 over k); weights staged from pre-transposed wt* with
// stride-1 conflict-free LDS writes.
// ---------------------------------------------------------------------------
__global__ __launch_bounds__(256, 2) void mlp_kernel(
    const float* __restrict__ xyz, const float* __restrict__ points,
    const int* __restrict__ fps_idx, const int* __restrict__ ball_idx,
    const float* __restrict__ wt0, const float* __restrict__ b0,
    const float* __restrict__ wt1, const float* __restrict__ b1,
    const float* __restrict__ wt2, const float* __restrict__ b2,
    float* __restrict__ out) {
  const int s = blockIdx.x, b = blockIdx.y, t = threadIdx.x;

  __shared__ float A1[64 * 36];    // layer0 out [o][k]
  __shared__ float A2[128 * 36];   // layer1 out [o][k]
  __shared__ float S[8704];        // scratch: A0+Wt0 | Wt1 | Wt2 chunk
  __shared__ float bias_sh[256];
  __shared__ int jidx[32];
  __shared__ float ctr[3];

  const int g = b * NCTR + s;

  // phase 1: indices, centroid, Wt0 [67][68] (stride-1 writes), bias0
  if (t < 32) jidx[t] = ball_idx[(size_t)g * 32 + t];
  if (t < 3) ctr[t] = xyz[((size_t)b * 3 + t) * NPTS + fps_idx[g]];
  float* A0 = S;              // [67][36]
  float* Wt0 = S + 67 * 36;   // [67][68]
  for (int e = t; e < 67 * 64; e += 256) {
    int c = e >> 6, o = e & 63;
    Wt0[c * 68 + o] = wt0[e];  // global coalesced, LDS stride-1
  }
  if (t < 64) bias_sh[t] = b0[t];
  __syncthreads();

  // phase 2: gather A0 = [xyz_norm(3); points(64)] x 32 samples
  for (int e = t; e < 67 * 32; e += 256) {
    int c = e >> 5, k = e & 31;
    int j = jidx[k];
    float v;
    if (c < 3)
      v = xyz[((size_t)b * 3 + c) * NPTS + j] - ctr[c];
    else
      v = points[((size_t)b * 64 + (c - 3)) * NPTS + j];
    A0[c * 36 + k] = v;
  }
  __syncthreads();

  // phase 3: layer 0 (67 -> 64), tile 4k x 2o
  {
    const int o0 = (t & 31) * 2;
    const int k0 = (t >> 5) * 4;
    float acc[4][2] = {{0.f, 0.f}, {0.f, 0.f}, {0.f, 0.f}, {0.f, 0.f}};
    for (int c = 0; c < 67; ++c) {
      const float4 a = *(const float4*)(A0 + c * 36 + k0);
      const float wv0 = Wt0[c * 68 + o0];
      const float wv1 = Wt0[c * 68 + o0 + 1];
      acc[0][0] = fmaf(a.x, wv0, acc[0][0]);
      acc[1][0] = fmaf(a.y, wv0, acc[1][0]);
      acc[2][0] = fmaf(a.z, wv0, acc[2][0]);
      acc[3][0] = fmaf(a.w, wv0, acc[3][0]);
      acc[0][1] = fmaf(a.x, wv1, acc[0][1]);
      acc[1][1] = fmaf(a.y, wv1, acc[1][1]);
      acc[2][1] = fmaf(a.z, wv1, acc[2][1]);
      acc[3][1] = fmaf(a.w, wv1, acc[3][1]);
    }
#pragma unroll
    for (int i = 0; i < 2; ++i) {
      const float bb = bias_sh[o0 + i];
      float4 r;
      r.x = silu_f(acc[0][i] + bb);
      r.y = silu_f(acc[1][i] + bb);
      r.z = silu_f(acc[2][i] + bb);
      r.w = silu_f(acc[3][i] + bb);
      *(float4*)(A1 + (o0 + i) * 36 + k0) = r;
    }
  }
  __syncthreads();

  // phase 4: stage Wt1 [64][132] (stride-1 writes), bias1
  float* Wt1 = S;
  for (int e = t; e < 128 * 64; e += 256) {
    int c = e >> 7, o = e & 127;
    Wt1[c * 132 + o] = wt1[e];
  }
  if (t < 128) bias_sh[t] = b1[t];
  __syncthreads();

  // phase 5: layer 1 (64 -> 128), tile 4k x 4o
  {
    const int o0 = (t & 31) * 4;
    const int k0 = (t >> 5) * 4;
    float acc[4][4];
#pragma unroll
    for (int kk = 0; kk < 4; ++kk)
#pragma unroll
      for (int oo = 0; oo < 4; ++oo) acc[kk][oo] = 0.f;
    for (int c = 0; c < 64; ++c) {
      const float4 a = *(const float4*)(A1 + c * 36 + k0);
      const float4 w = *(const float4*)(Wt1 + c * 132 + o0);
      const float av[4] = {a.x, a.y, a.z, a.w};
      const float wv[4] = {w.x, w.y, w.z, w.w};
#pragma unroll
      for (int kk = 0; kk < 4; ++kk)
#pragma unroll
        for (int oo = 0; oo < 4; ++oo)
          acc[kk][oo] = fmaf(av[kk], wv[oo], acc[kk][oo]);
    }
#pragma unroll
    for (int oo = 0; oo < 4; ++oo) {
      const float bb = bias_sh[o0 + oo];
      float4 r;
      r.x = silu_f(acc[0][oo] + bb);
      r.y = silu_f(acc[1][oo] + bb);
      r.z = silu_f(acc[2][oo] + bb);
      r.w = silu_f(acc[3][oo] + bb);
      *(float4*)(A2 + (o0 + oo) * 36 + k0) = r;
    }
  }
  __syncthreads();

  // phase 6: layer 2 (128 -> 256) in 4 chunks of 64 outputs + mean over k
  float* Wt2 = S;   // [128][68] per chunk
  float* P = A1;    // partial sums [64][9] (A1 dead)
  const int o0 = (t & 31) * 2;
  const int k0 = (t >> 5) * 4;
  const int kg = t >> 5;
  for (int chunk = 0; chunk < 4; ++chunk) {
    for (int e = t; e < 64 * 128; e += 256) {
      int c = e >> 6, o = e & 63;
      Wt2[c * 68 + o] = wt2[c * 256 + chunk * 64 + o];  // coalesced / stride-1
    }
    if (t < 64) bias_sh[t] = b2[chunk * 64 + t];
    __syncthreads();

    float acc[4][2] = {{0.f, 0.f}, {0.f, 0.f}, {0.f, 0.f}, {0.f, 0.f}};
    for (int c = 0; c < 128; ++c) {
      const float4 a = *(const float4*)(A2 + c * 36 + k0);
      const float wv0 = Wt2[c * 68 + o0];
      const float wv1 = Wt2[c * 68 + o0 + 1];
      acc[0][0] = fmaf(a.x, wv0, acc[0][0]);
      acc[1][0] = fmaf(a.y, wv0, acc[1][0]);
      acc[2][0] = fmaf(a.z, wv0, acc[2][0]);
      acc[3][0] = fmaf(a.w, wv0, acc[3][0]);
      acc[0][1] = fmaf(a.x, wv1, acc[0][1]);
      acc[1][1] = fmaf(a.y, wv1, acc[1][1]);
      acc[2][1] = fmaf(a.z, wv1, acc[2][1]);
      acc[3][1] = fmaf(a.w, wv1, acc[3][1]);
    }
#pragma unroll
    for (int i = 0; i < 2; ++i) {
      const float bb = bias_sh[o0 + i];
      float sum = silu_f(acc[0][i] + bb) + silu_f(acc[1][i] + bb) +
                  silu_f(acc[2][i] + bb) + silu_f(acc[3][i] + bb);
      P[(o0 + i) * 9 + kg] = sum;
    }
    __syncthreads();
    if (t < 64) {
      float tot = 0.f;
#pragma unroll
      for (int q = 0; q < 8; ++q) tot += P[t * 9 + q];
      out[((size_t)b * 256 + chunk * 64 + t) * NCTR + s] = tot * (1.0f / 32.0f);
    }
    __syncthreads();
  }
}

extern "C" void kernel_launch(void* const* d_in, const int* in_sizes, int n_in,
                              void* d_out, int out_size, void* d_ws, size_t ws_size,
                              hipStream_t stream) {
  const float* xyz = (const float*)d_in[0];
  const float* points = (const float*)d_in[1];
  const float* w0 = (const float*)d_in[2];
  const float* b0 = (const float*)d_in[3];
  const float* w1 = (const float*)d_in[4];
  const float* b1 = (const float*)d_in[5];
  const float* w2 = (const float*)d_in[6];
  const float* b2 = (const float*)d_in[7];
  float* out = (float*)d_out;

  int* fps = (int*)d_ws;           // 8*1024 ints
  int* bidx = (int*)d_ws + 8192;   // 8*1024*32 ints
  float* wt0 = (float*)d_ws + 270336;         // 67*64
  float* wt1 = wt0 + 67 * 64;                 // 64*128
  float* wt2 = wt1 + 64 * 128;                // 128*256  (total ws ~1.27 MB)

  transpose_w_kernel<<<64, 256, 0, stream>>>(w0, w1, w2, wt0, wt1, wt2);
  fps_kernel<<<BATCH, 512, 0, stream>>>(xyz, fps);
  ballq_kernel<<<2048, 256, 0, stream>>>(xyz, fps, bidx);
  mlp_kernel<<<dim3(NCTR, BATCH), 256, 0, stream>>>(xyz, points, fps, bidx,
                                                    wt0, b0, wt1, b1, wt2, b2, out);
}